// Round 14
// baseline (494.488 us; speedup 1.0000x reference)
//
#include <hip/hip_runtime.h>
#include <cstdint>
#include <cstddef>

// SummaryAdapter fused kernel for MI355X (gfx950), v14 = R8 (best, 315us) +
// h kept in registers: P1's staging regs (pack4'd bf16) are saved into
// hreg[8][4] (32 VGPR) and P5 adds the residual from registers -> zero
// global h re-reads (removes 8 L3-latency chains/block + L1 port traffic,
// and the L3-capacity coupling that sank R13). Both chunk loops fully
// unrolled so all hreg indices are compile-time (no scratch).
// Everything else identical to R8. L=8 B=2 S=4096 D=2048 N=128 Ds=1024 Da=64.
//
// LDS map (24832 B, 6 blocks/CU), as R8:
//   stage 2 x [16][512B bf16 swz] @0..16384; after P1: qsc s66 @0,
//   Pb u16 s136 @4352, aob s66 @8704; scb f32 s132 @16384; resb u16 s520 @16384.
//
// Workspace layout (bytes):          off      size
//   KF  frag bf16                      0    262144
//   VF  frag bf16                 262144    262144
//   WqF frag bf16                 524288   2097152
//   WoF frag bf16                2621440   2097152
// Requires ws_size >= 4718592.

typedef __attribute__((ext_vector_type(8))) short short8;   // 8 x bf16
typedef __attribute__((ext_vector_type(4))) float f32x4;
typedef __attribute__((ext_vector_type(4))) unsigned short u16x4;

#define MFMA16(a, b, c) __builtin_amdgcn_mfma_f32_16x16x32_bf16((a), (b), (c), 0, 0, 0)

__device__ __forceinline__ unsigned short f2bf(float f) {
  unsigned int x = __builtin_bit_cast(unsigned int, f);
  x += 0x7fffu + ((x >> 16) & 1u);        // RNE
  return (unsigned short)(x >> 16);
}
__device__ __forceinline__ float bf2f(unsigned short u) {
  return __builtin_bit_cast(float, (unsigned int)u << 16);
}
__device__ __forceinline__ short8 cvt8v(f32x4 a, f32x4 b) {
  short8 r;
  r[0] = (short)f2bf(a[0]); r[1] = (short)f2bf(a[1]);
  r[2] = (short)f2bf(a[2]); r[3] = (short)f2bf(a[3]);
  r[4] = (short)f2bf(b[0]); r[5] = (short)f2bf(b[1]);
  r[6] = (short)f2bf(b[2]); r[7] = (short)f2bf(b[3]);
  return r;
}
__device__ __forceinline__ short8 ld_cvt8(const float* p) {
  f32x4 v0 = *(const f32x4*)p, v1 = *(const f32x4*)(p + 4);
  return cvt8v(v0, v1);
}
__device__ __forceinline__ u16x4 pack4(f32x4 v) {
  u16x4 r;
  r[0] = f2bf(v[0]); r[1] = f2bf(v[1]); r[2] = f2bf(v[2]); r[3] = f2bf(v[3]);
  return r;
}

// ---------------- pre 1: K = bank@Wk^T, V = bank@Wv^T via MFMA -------------
__global__ __launch_bounds__(64)
void pre_kv_kernel(const float* __restrict__ bank,
                   const float* __restrict__ Wk,
                   const float* __restrict__ Wv,
                   unsigned short* __restrict__ KF, unsigned short* __restrict__ VF) {
  int bid = blockIdx.x;
  int at = bid & 3, nt = (bid >> 2) & 7, kv = (bid >> 5) & 1;
  int b = (bid >> 6) & 1, l = bid >> 7;
  int lane = threadIdx.x & 63;
  int lo = lane & 15, hi = lane >> 4;
  const float* W  = (kv ? Wv : Wk) + (size_t)l * 65536;
  const float* bk = bank + (size_t)b * 131072;
  int lbq = l * 2 + b;
  f32x4 acc = (f32x4){0.f, 0.f, 0.f, 0.f};
  for (int ks = 0; ks < 32; ++ks) {
    short8 A = ld_cvt8(bk + (nt * 16 + lo) * 1024 + ks * 32 + hi * 8);
    short8 B = ld_cvt8(W + (at * 16 + lo) * 1024 + ks * 32 + hi * 8);
    acc = MFMA16(A, B, acc);
  }
  for (int r = 0; r < 4; ++r) {
    int n = nt * 16 + hi * 4 + r;
    int a = at * 16 + lo;
    unsigned short v = f2bf(acc[r]);
    if (kv == 0) {
      int idx = ((lbq * 8 + (n >> 4)) * 2 + (a >> 5)) * 512 +
                (((a >> 3) & 3) * 16 + (n & 15)) * 8 + (a & 7);
      KF[idx] = v;
    } else {
      int idx = ((lbq * 4 + (a >> 4)) * 4 + (n >> 5)) * 512 +
                (((n >> 3) & 3) * 16 + (a & 15)) * 8 + (n & 7);
      VF[idx] = v;
    }
  }
}

// ---------------- pre 2: Wq/Wo -> bf16 fragment layout ---------------------
__global__ void pre_frag_kernel(const float* __restrict__ Wq, const float* __restrict__ Wo,
                                unsigned short* __restrict__ WqF, unsigned short* __restrict__ WoF) {
  int idx = blockIdx.x * 256 + threadIdx.x;        // 262144 threads
  if (idx < 131072) {
    int t = idx;
    int lane = t & 63, ks = (t >> 6) & 63, at = (t >> 12) & 3, l = t >> 14;
    int a = at * 16 + (lane & 15), d = ks * 32 + (lane >> 4) * 8;
    *(short8*)(WqF + (size_t)t * 8) = ld_cvt8(Wq + ((size_t)(l * 64 + a)) * 2048 + d);
  } else {
    int t = idx - 131072;
    int lane = t & 63, ks = (t >> 6) & 1, dt = (t >> 7) & 127, l = t >> 14;
    int d = dt * 16 + (lane & 15), a = ks * 32 + (lane >> 4) * 8;
    *(short8*)(WoF + (size_t)t * 8) = ld_cvt8(Wo + ((size_t)(l * 2048 + d)) * 64 + a);
  }
}

// ---------------- main fused kernel ----------------------------------------
// 4096 blocks x 256 threads (4 waves), block owns one 16-row s-tile.
// 24832 B LDS -> 6 blocks/CU; h lives in hreg[8][4] (bf16) for the epilogue.
__global__ __launch_bounds__(256, 6)
void adapter_main(const float* __restrict__ hidden,
                  const unsigned short* __restrict__ KF, const unsigned short* __restrict__ VF,
                  const unsigned short* __restrict__ WqF, const unsigned short* __restrict__ WoF,
                  const float* __restrict__ gates, float* __restrict__ out) {
  __shared__ __align__(16) char smem[24832];
  float* qsc = (float*)smem;                        // [16] s66 f32
  unsigned short* Pb = (unsigned short*)(smem + 4352);  // [16] s136 u16
  float* aob = (float*)(smem + 8704);               // [16] s66 f32
  float* scb = (float*)(smem + 16384);              // [16] s132 f32
  char* resb = smem + 16384;                        // u16 [16] s520

  // XCD-bijective swizzle (4096 % 8 == 0): XCD x gets 512 tiles = layer x.
  int bid0 = blockIdx.x;
  int bid = (bid0 & 7) * 512 + (bid0 >> 3);
  int st = bid & 255, b = (bid >> 8) & 1, l = bid >> 9;
  int tid = threadIdx.x, wave = tid >> 6, lane = tid & 63;
  int lo = lane & 15, hi = lane >> 4;
  size_t hbase = ((size_t)(l * 2 + b) * 4096 + st * 16) * 2048;
  const char* hby = (const char*)(hidden + hbase);
  float gate = 1.0f / (1.0f + __expf(-gates[l]));
  int lb = l * 2 + b;
  int at = wave;

  u16x4 hreg[8][4];                                // this thread's h, bf16

  // ---- Phase 1: Q = h @ Wq^T; 8 chunks of 16 rows x 1KB, dbuf staging ----
  f32x4 sreg[4];
  f32x4 qacc = (f32x4){0.f, 0.f, 0.f, 0.f};
  {
    const unsigned short* wqb = WqF + ((size_t)(l * 4 + at) * 64) * 512 + lane * 8;

#define LOADC(c)                                                             \
    _Pragma("unroll")                                                        \
    for (int s2 = 0; s2 < 4; ++s2) {                                         \
      int row = s2 * 4 + wave;                                               \
      sreg[s2] = *(const f32x4*)(hby + (size_t)row * 8192 + (size_t)(c) * 1024 + lane * 16); \
    }
#define WRITEC(c)                                                            \
    _Pragma("unroll")                                                        \
    for (int s2 = 0; s2 < 4; ++s2) {                                         \
      int row = s2 * 4 + wave;                                               \
      u16x4 pk = pack4(sreg[s2]);                                            \
      hreg[(c)][s2] = pk;                                                    \
      *(u16x4*)(smem + ((c) & 1) * 8192 + row * 512 + ((lane * 8) ^ ((row & 7) << 4))) = pk; \
    }

    LOADC(0); WRITEC(0);
    #pragma unroll
    for (int c = 0; c < 8; ++c) {
      __syncthreads();                           // chunk c LDS visible
      if (c < 7) LOADC(c + 1);
      const char* rb = smem + (c & 1) * 8192 + lo * 512;
      int sw = (lo & 7) << 4;
      #pragma unroll
      for (int ks = 0; ks < 8; ++ks) {
        short8 A = *(const short8*)(rb + ((ks * 64 + hi * 16) ^ sw));
        short8 B = *(const short8*)(wqb + (size_t)(c * 8 + ks) * 512);
        qacc = MFMA16(A, B, qacc);
      }
      if (c < 7) WRITEC(c + 1);
    }
#undef LOADC
#undef WRITEC
  }

  // ---- write Q (scaled) -> qsc (stage buf0; all waves past chunk-6 reads) ----
  #pragma unroll
  for (int r = 0; r < 4; ++r)                      // fold 1/sqrt(64)
    qsc[(hi * 4 + r) * 68 + at * 16 + lo] = qacc[r] * 0.125f;
  __syncthreads();

  // ---- Phase 2: scores = Q @ K^T -> scb ----
  {
    short8 afrag[2];
    #pragma unroll
    for (int ks = 0; ks < 2; ++ks) {
      const float* qp = qsc + lo * 68 + ks * 32 + hi * 8;
      afrag[ks] = cvt8v(*(const f32x4*)qp, *(const f32x4*)(qp + 4));
    }
    #pragma unroll
    for (int i = 0; i < 2; ++i) {
      int nt = wave * 2 + i;
      f32x4 acc = (f32x4){0.f, 0.f, 0.f, 0.f};
      const unsigned short* kf = KF + ((size_t)(lb * 8 + nt) * 2) * 512 + lane * 8;
      acc = MFMA16(afrag[0], *(const short8*)(kf), acc);
      acc = MFMA16(afrag[1], *(const short8*)(kf + 512), acc);
      #pragma unroll
      for (int r = 0; r < 4; ++r)
        scb[(hi * 4 + r) * 132 + nt * 16 + lo] = acc[r];
    }
  }
  __syncthreads();

  // ---- Phase 3: softmax over N=128 (16 lanes per row) -> Pb bf16 ----
  {
    int row = wave * 4 + hi;
    const float* sp = scb + row * 132 + lo * 8;
    f32x4 v0 = *(const f32x4*)sp, v1 = *(const f32x4*)(sp + 4);
    float m = fmaxf(fmaxf(fmaxf(v0[0], v0[1]), fmaxf(v0[2], v0[3])),
                    fmaxf(fmaxf(v1[0], v1[1]), fmaxf(v1[2], v1[3])));
    m = fmaxf(m, __shfl_xor(m, 1)); m = fmaxf(m, __shfl_xor(m, 2));
    m = fmaxf(m, __shfl_xor(m, 4)); m = fmaxf(m, __shfl_xor(m, 8));
    f32x4 e0, e1; float s = 0.f;
    #pragma unroll
    for (int j = 0; j < 4; ++j) { e0[j] = __expf(v0[j] - m); s += e0[j]; }
    #pragma unroll
    for (int j = 0; j < 4; ++j) { e1[j] = __expf(v1[j] - m); s += e1[j]; }
    s += __shfl_xor(s, 1); s += __shfl_xor(s, 2);
    s += __shfl_xor(s, 4); s += __shfl_xor(s, 8);
    float inv = 1.0f / s;
    #pragma unroll
    for (int j = 0; j < 4; ++j) { e0[j] *= inv; e1[j] *= inv; }
    *(short8*)((char*)Pb + row * 272 + lo * 16) = cvt8v(e0, e1);
  }
  __syncthreads();

  // ---- Phase 4: attn_out = P @ V -> aob ----
  {
    short8 pfrag[4];
    #pragma unroll
    for (int ks = 0; ks < 4; ++ks)
      pfrag[ks] = *(const short8*)((const char*)Pb + lo * 272 + ks * 64 + hi * 16);
    const unsigned short* vf = VF + ((size_t)(lb * 4 + at) * 4) * 512 + lane * 8;
    f32x4 a = (f32x4){0.f, 0.f, 0.f, 0.f};
    #pragma unroll
    for (int ks = 0; ks < 4; ++ks)
      a = MFMA16(pfrag[ks], *(const short8*)(vf + (size_t)ks * 512), a);
    #pragma unroll
    for (int r = 0; r < 4; ++r)
      aob[(hi * 4 + r) * 68 + at * 16 + lo] = a[r];
  }
  __syncthreads();

  // ---- Phase 5: 8 d-chunks of 256 cols: resid MFMA -> LDS -> reg-h add ----
  {
    short8 bfrag[2];
    #pragma unroll
    for (int ks = 0; ks < 2; ++ks) {
      const float* ap2 = aob + lo * 68 + ks * 32 + hi * 8;
      bfrag[ks] = cvt8v(*(const f32x4*)ap2, *(const f32x4*)(ap2 + 4));
    }
    char* ob = (char*)(out + hbase);
    #pragma unroll
    for (int c = 0; c < 8; ++c) {
      #pragma unroll
      for (int j = 0; j < 4; ++j) {
        int dtl = wave * 4 + j;                    // 0..15 within chunk
        int dt = c * 16 + dtl;
        const unsigned short* wo = WoF + ((size_t)(l * 128 + dt) * 2) * 512 + lane * 8;
        short8 A0 = *(const short8*)(wo);
        short8 A1 = *(const short8*)(wo + 512);
        f32x4 acc = (f32x4){0.f, 0.f, 0.f, 0.f};
        acc = MFMA16(A0, bfrag[0], acc);
        acc = MFMA16(A1, bfrag[1], acc);
        // resid^T frag: s = lo, d_local = dtl*16 + hi*4 + r
        *(u16x4*)(resb + lo * 520 + dtl * 32 + hi * 8) = pack4(acc);
      }
      __syncthreads();                             // resid chunk ready
      #pragma unroll
      for (int i2 = 0; i2 < 4; ++i2) {
        int row = i2 * 4 + wave;                   // 1 row per wave-instr
        size_t off = (size_t)row * 8192 + (size_t)c * 1024 + lane * 16;
        u16x4 hv = hreg[c][i2];                    // h from registers (bf16)
        u16x4 rv = *(const u16x4*)(resb + row * 520 + lane * 8);
        f32x4 o;
        #pragma unroll
        for (int r = 0; r < 4; ++r) o[r] = bf2f(hv[r]) + gate * bf2f(rv[r]);
        __builtin_nontemporal_store(o, (f32x4*)(ob + off));
      }
      __syncthreads();                             // resb reads done
    }
  }
}

extern "C" void kernel_launch(void* const* d_in, const int* in_sizes, int n_in,
                              void* d_out, int out_size, void* d_ws, size_t ws_size,
                              hipStream_t stream) {
  const float* hidden = (const float*)d_in[0];
  const float* bank   = (const float*)d_in[1];
  const float* Wq     = (const float*)d_in[2];
  const float* Wk     = (const float*)d_in[3];
  const float* Wv     = (const float*)d_in[4];
  const float* Wo     = (const float*)d_in[5];
  const float* gates  = (const float*)d_in[6];
  float* out = (float*)d_out;

  char* ws = (char*)d_ws;
  unsigned short* KF  = (unsigned short*)(ws);
  unsigned short* VF  = (unsigned short*)(ws + 262144);
  unsigned short* WqF = (unsigned short*)(ws + 524288);
  unsigned short* WoF = (unsigned short*)(ws + 2621440);

  pre_kv_kernel<<<1024, 64, 0, stream>>>(bank, Wk, Wv, KF, VF);
  pre_frag_kernel<<<1024, 256, 0, stream>>>(Wq, Wo, WqF, WoF);
  adapter_main<<<4096, 256, 0, stream>>>(hidden, KF, VF, WqF, WoF, gates, out);
}

// Round 15
// 352.012 us; speedup vs baseline: 1.4047x; 1.4047x over previous
//
#include <hip/hip_runtime.h>
#include <cstdint>
#include <cstddef>

// SummaryAdapter fused kernel for MI355X (gfx950), v15: 1-wave blocks, ZERO
// barriers. h streamed via global_load_lds (8KB chunks, 1KB row-pair instrs,
// source-swizzled for conflict-free reads), depth-1 vmcnt(0) FIFO with weight
// loads issued BEFORE the next DMA (consuming them never drains the pipe).
// Every wave is an independent pipeline with 8KB permanently in flight;
// 6 waves/CU -> 48KB outstanding/CU. In-register softmax. P5 re-streams h
// (L3-hit) identically; stores ride the FIFO.
// L=8 B=2 S=4096 D=2048 N=128 Ds=1024 Da=64.
//
// LDS (24960 B -> 6 blocks/CU): stage 2x8192 @0; qs 4352 @16384; resb 4224 @20736.
//
// Workspace layout (bytes):          off      size
//   KF  frag bf16                      0    262144
//   VF  frag bf16                 262144    262144
//   WqF frag bf16                 524288   2097152
//   WoF frag bf16                2621440   2097152
// Requires ws_size >= 4718592.

typedef __attribute__((ext_vector_type(8))) short short8;   // 8 x bf16
typedef __attribute__((ext_vector_type(4))) float f32x4;
typedef __attribute__((ext_vector_type(4))) unsigned short u16x4;

#define MFMA16(a, b, c) __builtin_amdgcn_mfma_f32_16x16x32_bf16((a), (b), (c), 0, 0, 0)
#define SB __builtin_amdgcn_sched_barrier(0)

__device__ __forceinline__ unsigned short f2bf(float f) {
  unsigned int x = __builtin_bit_cast(unsigned int, f);
  x += 0x7fffu + ((x >> 16) & 1u);        // RNE
  return (unsigned short)(x >> 16);
}
__device__ __forceinline__ float bf2f(unsigned short u) {
  return __builtin_bit_cast(float, (unsigned int)u << 16);
}
__device__ __forceinline__ short8 cvt8v(f32x4 a, f32x4 b) {
  short8 r;
  r[0] = (short)f2bf(a[0]); r[1] = (short)f2bf(a[1]);
  r[2] = (short)f2bf(a[2]); r[3] = (short)f2bf(a[3]);
  r[4] = (short)f2bf(b[0]); r[5] = (short)f2bf(b[1]);
  r[6] = (short)f2bf(b[2]); r[7] = (short)f2bf(b[3]);
  return r;
}
__device__ __forceinline__ short8 ld_cvt8(const float* p) {
  f32x4 v0 = *(const f32x4*)p, v1 = *(const f32x4*)(p + 4);
  return cvt8v(v0, v1);
}
__device__ __forceinline__ u16x4 pack4(f32x4 v) {
  u16x4 r;
  r[0] = f2bf(v[0]); r[1] = f2bf(v[1]); r[2] = f2bf(v[2]); r[3] = f2bf(v[3]);
  return r;
}
__device__ __forceinline__ void gload_lds16(const void* g, void* l) {
  typedef __attribute__((address_space(1))) const unsigned int gu32;
  typedef __attribute__((address_space(3))) unsigned int lu32;
  __builtin_amdgcn_global_load_lds((gu32*)(const unsigned int*)g,
                                   (lu32*)(unsigned int*)l, 16, 0, 0);
}

// ---------------- pre 1: K = bank@Wk^T, V = bank@Wv^T via MFMA -------------
__global__ __launch_bounds__(64)
void pre_kv_kernel(const float* __restrict__ bank,
                   const float* __restrict__ Wk,
                   const float* __restrict__ Wv,
                   unsigned short* __restrict__ KF, unsigned short* __restrict__ VF) {
  int bid = blockIdx.x;
  int at = bid & 3, nt = (bid >> 2) & 7, kv = (bid >> 5) & 1;
  int b = (bid >> 6) & 1, l = bid >> 7;
  int lane = threadIdx.x & 63;
  int lo = lane & 15, hi = lane >> 4;
  const float* W  = (kv ? Wv : Wk) + (size_t)l * 65536;
  const float* bk = bank + (size_t)b * 131072;
  int lbq = l * 2 + b;
  f32x4 acc = (f32x4){0.f, 0.f, 0.f, 0.f};
  for (int ks = 0; ks < 32; ++ks) {
    short8 A = ld_cvt8(bk + (nt * 16 + lo) * 1024 + ks * 32 + hi * 8);
    short8 B = ld_cvt8(W + (at * 16 + lo) * 1024 + ks * 32 + hi * 8);
    acc = MFMA16(A, B, acc);
  }
  for (int r = 0; r < 4; ++r) {
    int n = nt * 16 + hi * 4 + r;
    int a = at * 16 + lo;
    unsigned short v = f2bf(acc[r]);
    if (kv == 0) {
      int idx = ((lbq * 8 + (n >> 4)) * 2 + (a >> 5)) * 512 +
                (((a >> 3) & 3) * 16 + (n & 15)) * 8 + (a & 7);
      KF[idx] = v;
    } else {
      int idx = ((lbq * 4 + (a >> 4)) * 4 + (n >> 5)) * 512 +
                (((n >> 3) & 3) * 16 + (a & 15)) * 8 + (n & 7);
      VF[idx] = v;
    }
  }
}

// ---------------- pre 2: Wq/Wo -> bf16 fragment layout ---------------------
__global__ void pre_frag_kernel(const float* __restrict__ Wq, const float* __restrict__ Wo,
                                unsigned short* __restrict__ WqF, unsigned short* __restrict__ WoF) {
  int idx = blockIdx.x * 256 + threadIdx.x;        // 262144 threads
  if (idx < 131072) {
    int t = idx;
    int lane = t & 63, ks = (t >> 6) & 63, at = (t >> 12) & 3, l = t >> 14;
    int a = at * 16 + (lane & 15), d = ks * 32 + (lane >> 4) * 8;
    *(short8*)(WqF + (size_t)t * 8) = ld_cvt8(Wq + ((size_t)(l * 64 + a)) * 2048 + d);
  } else {
    int t = idx - 131072;
    int lane = t & 63, ks = (t >> 6) & 1, dt = (t >> 7) & 127, l = t >> 14;
    int d = dt * 16 + (lane & 15), a = ks * 32 + (lane >> 4) * 8;
    *(short8*)(WoF + (size_t)t * 8) = ld_cvt8(Wo + ((size_t)(l * 2048 + d)) * 64 + a);
  }
}

// ---------------- main fused kernel ----------------------------------------
// 4096 blocks x 64 threads (1 wave each). Wave owns a 16-row tile.
__global__ __launch_bounds__(64, 1)
void adapter_main(const float* __restrict__ hidden,
                  const unsigned short* __restrict__ KF, const unsigned short* __restrict__ VF,
                  const unsigned short* __restrict__ WqF, const unsigned short* __restrict__ WoF,
                  const float* __restrict__ gates, float* __restrict__ out) {
  __shared__ __align__(1024) char smem[24960];
  char* stg = smem;                                   // 2 x 8192 stage
  float* qs = (float*)(smem + 16384);                 // 4352 B scratch
  unsigned short* qsu = (unsigned short*)(smem + 16384);
  char* resb = smem + 20736;                          // u16 [16][132] (264 B/row)

  // XCD-bijective swizzle (4096 % 8 == 0): XCD x gets 512 tiles = layer x.
  int bid0 = blockIdx.x;
  int bid = (bid0 & 7) * 512 + (bid0 >> 3);
  int st = bid & 255, b = (bid >> 8) & 1, l = bid >> 9;
  int lane = threadIdx.x & 63;
  int lo = lane & 15, hi = lane >> 4;
  int lh = lane >> 5, s16 = (lane & 31) * 16;
  size_t hbase = ((size_t)(l * 2 + b) * 4096 + st * 16) * 2048;
  const char* hby = (const char*)(hidden + hbase);
  float gate = 1.0f / (1.0f + __expf(-gates[l]));
  int lb = l * 2 + b;

  // DMA of one 16-row x 512B chunk: 8 instrs, instr i = rows 2i,2i+1 (1KB).
  // Global source swizzled (slot^(row&7)) so LDS reads are ~2-way max.
#define DMA_TILE(basebyte, buf)                                              \
  do {                                                                       \
    _Pragma("unroll")                                                        \
    for (int i_ = 0; i_ < 8; ++i_) {                                         \
      int row_ = 2 * i_ + lh;                                                \
      size_t g_ = (size_t)row_ * 8192 + (size_t)(s16 ^ ((row_ & 7) << 4));   \
      gload_lds16(hby + (size_t)(basebyte) + g_, stg + (buf) * 8192 + i_ * 1024); \
    }                                                                        \
  } while (0)
#define WAITDMA asm volatile("s_waitcnt vmcnt(0)" ::: "memory")

  // ---- Phase 1: Q = h @ Wq^T; 16 chunks of 16 x 128 f32; depth-1 FIFO ----
  f32x4 qacc[4];
  #pragma unroll
  for (int at = 0; at < 4; ++at) qacc[at] = (f32x4){0.f, 0.f, 0.f, 0.f};
  {
    const unsigned short* wqb = WqF + ((size_t)l * 256) * 512 + lane * 8;
    DMA_TILE(0, 0);
    #pragma unroll 1
    for (int c = 0; c < 16; ++c) {
      WAITDMA; SB;                                 // own DMA(c) landed
      short8 Bf[4][4];                             // weight loads FIRST (FIFO)
      #pragma unroll
      for (int at = 0; at < 4; ++at)
        #pragma unroll
        for (int ks = 0; ks < 4; ++ks)
          Bf[at][ks] = *(const short8*)(wqb + (size_t)(at * 64 + c * 4 + ks) * 512);
      SB;
      if (c < 15) DMA_TILE((c + 1) * 512, (c + 1) & 1);   // then next DMA
      SB;
      const char* rb = stg + (c & 1) * 8192 + lo * 512;
      int swz = (lo & 7) << 4;
      #pragma unroll
      for (int ks = 0; ks < 4; ++ks) {
        f32x4 v0 = *(const f32x4*)(rb + ((ks * 128 + hi * 32) ^ swz));
        f32x4 v1 = *(const f32x4*)(rb + ((ks * 128 + hi * 32 + 16) ^ swz));
        short8 A = cvt8v(v0, v1);
        #pragma unroll
        for (int at = 0; at < 4; ++at)
          qacc[at] = MFMA16(A, Bf[at][ks], qacc[at]);
      }
    }
  }

  // ---- write Q (scaled) to qs scratch ----
  #pragma unroll
  for (int at = 0; at < 4; ++at)
    #pragma unroll
    for (int r = 0; r < 4; ++r)
      qs[(hi * 4 + r) * 68 + at * 16 + lo] = qacc[at][r] * 0.125f;

  // ---- Phase 2: scores = Q @ K^T, all 8 n-tiles in registers ----
  f32x4 sacc[8];
  {
    short8 afrag[2];
    #pragma unroll
    for (int ks = 0; ks < 2; ++ks) {
      const float* qp = qs + lo * 68 + ks * 32 + hi * 8;
      afrag[ks] = cvt8v(*(const f32x4*)qp, *(const f32x4*)(qp + 4));
    }
    const unsigned short* kf = KF + ((size_t)lb * 16) * 512 + lane * 8;
    short8 kfr[8][2];
    #pragma unroll
    for (int nt = 0; nt < 8; ++nt) {
      kfr[nt][0] = *(const short8*)(kf + (size_t)nt * 1024);
      kfr[nt][1] = *(const short8*)(kf + (size_t)nt * 1024 + 512);
    }
    #pragma unroll
    for (int nt = 0; nt < 8; ++nt) {
      f32x4 a0 = (f32x4){0.f, 0.f, 0.f, 0.f};
      a0 = MFMA16(afrag[0], kfr[nt][0], a0);
      sacc[nt] = MFMA16(afrag[1], kfr[nt][1], a0);
    }
  }

  // ---- Phase 3: in-register softmax (row = hi*4+r, cols over lo) ----
  {
    #pragma unroll
    for (int r = 0; r < 4; ++r) {
      float m = sacc[0][r];
      #pragma unroll
      for (int nt = 1; nt < 8; ++nt) m = fmaxf(m, sacc[nt][r]);
      m = fmaxf(m, __shfl_xor(m, 1)); m = fmaxf(m, __shfl_xor(m, 2));
      m = fmaxf(m, __shfl_xor(m, 4)); m = fmaxf(m, __shfl_xor(m, 8));
      float s = 0.f;
      #pragma unroll
      for (int nt = 0; nt < 8; ++nt) {
        float e = __expf(sacc[nt][r] - m);
        sacc[nt][r] = e; s += e;
      }
      s += __shfl_xor(s, 1); s += __shfl_xor(s, 2);
      s += __shfl_xor(s, 4); s += __shfl_xor(s, 8);
      float inv = 1.0f / s;
      #pragma unroll
      for (int nt = 0; nt < 8; ++nt) sacc[nt][r] *= inv;
    }
    #pragma unroll
    for (int nt = 0; nt < 8; ++nt)                 // P bf16 [16][136], 272 B/row
      #pragma unroll
      for (int r = 0; r < 4; ++r)
        qsu[(hi * 4 + r) * 136 + nt * 16 + lo] = f2bf(sacc[nt][r]);
  }

  // ---- Phase 4: attn_out = P @ V; issue P5's first DMA mid-phase ----
  {
    short8 pfrag[4];
    #pragma unroll
    for (int ks = 0; ks < 4; ++ks)
      pfrag[ks] = *(const short8*)((const char*)qsu + lo * 272 + ks * 64 + hi * 16);
    const unsigned short* vf = VF + ((size_t)lb * 16) * 512 + lane * 8;
    short8 vfr[16];
    #pragma unroll
    for (int q = 0; q < 16; ++q)
      vfr[q] = *(const short8*)(vf + (size_t)q * 512);
    SB;
    DMA_TILE(0, 0);                                // P5 chunk 0 (overlaps P4)
    SB;
    f32x4 ao[4];
    #pragma unroll
    for (int at = 0; at < 4; ++at) {
      f32x4 a = (f32x4){0.f, 0.f, 0.f, 0.f};
      #pragma unroll
      for (int ks = 0; ks < 4; ++ks)
        a = MFMA16(pfrag[ks], vfr[at * 4 + ks], a);
      ao[at] = a;
    }
    #pragma unroll
    for (int at = 0; at < 4; ++at)
      #pragma unroll
      for (int r = 0; r < 4; ++r)
        qs[(hi * 4 + r) * 68 + at * 16 + lo] = ao[at][r];
  }

  // ---- Phase 5: 16 d-chunks of 128 cols; resid MFMA -> resb -> add+store ----
  {
    short8 bfrag[2];
    #pragma unroll
    for (int ks = 0; ks < 2; ++ks) {
      const float* ap2 = qs + lo * 68 + ks * 32 + hi * 8;
      bfrag[ks] = cvt8v(*(const f32x4*)ap2, *(const f32x4*)(ap2 + 4));
    }
    const unsigned short* wob = WoF + (size_t)l * 131072 + lane * 8;
    char* ob = (char*)(out + hbase);
    #pragma unroll 1
    for (int c = 0; c < 16; ++c) {
      WAITDMA; SB;                                 // DMA(c) landed (stores done)
      short8 W0[8], W1[8];                         // Wo loads FIRST (FIFO)
      #pragma unroll
      for (int j = 0; j < 8; ++j) {
        const unsigned short* wo = wob + (size_t)((c * 8 + j) * 2) * 512;
        W0[j] = *(const short8*)(wo);
        W1[j] = *(const short8*)(wo + 512);
      }
      SB;
      if (c < 15) DMA_TILE((c + 1) * 512, (c + 1) & 1);
      SB;
      #pragma unroll
      for (int j = 0; j < 8; ++j) {
        f32x4 acc = (f32x4){0.f, 0.f, 0.f, 0.f};
        acc = MFMA16(W0[j], bfrag[0], acc);
        acc = MFMA16(W1[j], bfrag[1], acc);
        *(u16x4*)(resb + lo * 264 + j * 32 + hi * 8) = pack4(acc);
      }
      const char* hb = stg + (c & 1) * 8192;
      #pragma unroll
      for (int i2 = 0; i2 < 8; ++i2) {
        int row = 2 * i2 + lh;
        f32x4 hv = *(const f32x4*)(hb + row * 512 + (s16 ^ ((row & 7) << 4)));
        u16x4 rv = *(const u16x4*)(resb + row * 264 + (lane & 31) * 8);
        f32x4 o;
        #pragma unroll
        for (int r = 0; r < 4; ++r) o[r] = hv[r] + gate * bf2f(rv[r]);
        __builtin_nontemporal_store(o,
            (f32x4*)(ob + (size_t)row * 8192 + (size_t)c * 512 + s16));
      }
    }
  }
#undef DMA_TILE
#undef WAITDMA
}

extern "C" void kernel_launch(void* const* d_in, const int* in_sizes, int n_in,
                              void* d_out, int out_size, void* d_ws, size_t ws_size,
                              hipStream_t stream) {
  const float* hidden = (const float*)d_in[0];
  const float* bank   = (const float*)d_in[1];
  const float* Wq     = (const float*)d_in[2];
  const float* Wk     = (const float*)d_in[3];
  const float* Wv     = (const float*)d_in[4];
  const float* Wo     = (const float*)d_in[5];
  const float* gates  = (const float*)d_in[6];
  float* out = (float*)d_out;

  char* ws = (char*)d_ws;
  unsigned short* KF  = (unsigned short*)(ws);
  unsigned short* VF  = (unsigned short*)(ws + 262144);
  unsigned short* WqF = (unsigned short*)(ws + 524288);
  unsigned short* WoF = (unsigned short*)(ws + 2621440);

  pre_kv_kernel<<<1024, 64, 0, stream>>>(bank, Wk, Wv, KF, VF);
  pre_frag_kernel<<<1024, 256, 0, stream>>>(Wq, Wo, WqF, WoF);
  adapter_main<<<4096, 64, 0, stream>>>(hidden, KF, VF, WqF, WoF, gates, out);
}